// Round 4
// baseline (620.061 us; speedup 1.0000x reference)
//
#include <hip/hip_runtime.h>
#include <math.h>

#define B_ROWS 512
#define D_DIM  512
#define C_CLS  100000
#define SCALE  64.0f
#define EPSN   1e-12f

#define BM 256
#define BN 64
#define BK 32
#define NKT (D_DIM / BK)    // 16
#define NTILE 1563          // ceil(100000/64)
#define NT2   (NTILE * 2)   // 32-class partial groups

typedef __attribute__((ext_vector_type(8))) short bf16x8;
typedef __attribute__((ext_vector_type(4))) float f32x4;

__device__ inline unsigned short f2bf(float f) {
    union { float f; unsigned int u; } v; v.f = f;
    unsigned int r = v.u + 0x7fffu + ((v.u >> 16) & 1u);
    return (unsigned short)(r >> 16);
}
__device__ inline float bf2f(unsigned short h) {
    union { unsigned int u; float f; } v; v.u = ((unsigned int)h) << 16;
    return v.f;
}
// packed f32->bf16 (RNE), 2 elems/instr
__device__ inline unsigned int cvtpk(float lo, float hi) {
    unsigned int r;
    asm("v_cvt_pk_bf16_f32 %0, %1, %2" : "=v"(r) : "v"(lo), "v"(hi));
    return r;
}

// ---------- normalize x rows, store bf16 (coalesced: lane, lane+64) ----------
__global__ void normalize_x(const float* __restrict__ x, unsigned short* __restrict__ xnb) {
    int row  = blockIdx.x;
    int lane = threadIdx.x;  // 64
    const float4* xr = (const float4*)(x + (size_t)row * D_DIM);
    float4 a = xr[lane];
    float4 b = xr[lane + 64];
    float ss = a.x*a.x + a.y*a.y + a.z*a.z + a.w*a.w
             + b.x*b.x + b.y*b.y + b.z*b.z + b.w*b.w;
    #pragma unroll
    for (int m = 1; m < 64; m <<= 1) ss += __shfl_xor(ss, m);
    float inv = 1.0f / fmaxf(sqrtf(ss), EPSN);
    ushort4 o0, o1;
    o0.x = f2bf(a.x*inv); o0.y = f2bf(a.y*inv); o0.z = f2bf(a.z*inv); o0.w = f2bf(a.w*inv);
    o1.x = f2bf(b.x*inv); o1.y = f2bf(b.y*inv); o1.z = f2bf(b.z*inv); o1.w = f2bf(b.w*inv);
    ushort4* orow = (ushort4*)(xnb + (size_t)row * D_DIM);
    orow[lane]      = o0;
    orow[lane + 64] = o1;
}

// ---------- fused GEMM: pure-register, no LDS, no barriers ----------
// Block: BM=256 x BN=64, 512 threads = 8 waves (4M x 2N); wave tile 64x32.
// A (xnb, L2-resident) loaded straight to bf16x8 fragments (quads cover full 64B lines).
// W (cold HBM stream) loaded f32 to regs with depth-1 prefetch, cvt_pk to bf16, ||w||^2
// accumulated per-lane. No __syncthreads anywhere -> no vmcnt(0) drains -> cold W misses
// stay in flight across K-steps; 16 waves/CU give TLP on top.
__global__ __launch_bounds__(512, 4) void gemm_fused(const unsigned short* __restrict__ xnb,
                                                     const float* __restrict__ w,
                                                     float2* __restrict__ partials) {
    int tid  = threadIdx.x;
    int m0   = blockIdx.x * BM;
    int c0   = blockIdx.y * BN;
    int wid  = tid >> 6;
    int lane = tid & 63;
    int quad = lane >> 4;
    int lr   = lane & 15;
    int wr   = wid >> 1;     // 0..3 : 64-row slice
    int wc   = wid & 1;      // 0..1 : 32-col slice

    f32x4 acc[4][2];
    #pragma unroll
    for (int i = 0; i < 4; i++)
        #pragma unroll
        for (int j = 0; j < 2; j++) {
            acc[i][j][0] = 0.f; acc[i][j][1] = 0.f; acc[i][j][2] = 0.f; acc[i][j][3] = 0.f;
        }

    // A fragment bases: lane (quad,lr) holds row m0+wr*64+i*16+lr, k = quad*8..quad*8+7
    const unsigned short* abase[4];
    #pragma unroll
    for (int i = 0; i < 4; i++)
        abase[i] = xnb + (size_t)(m0 + wr * 64 + i * 16 + lr) * D_DIM + quad * 8;

    // W: this lane's two classes (C/D col = lane&15 -> class c0+wc*32+j*16+lr)
    int cj0 = c0 + wc * 32 + lr;
    int cj1 = cj0 + 16;
    int valid0 = cj0 < C_CLS, valid1 = cj1 < C_CLS;
    if (cj0 >= C_CLS) cj0 = C_CLS - 1;
    if (cj1 >= C_CLS) cj1 = C_CLS - 1;
    const float* wb0 = w + (size_t)cj0 * D_DIM + quad * 8;
    const float* wb1 = w + (size_t)cj1 * D_DIM + quad * 8;

    float ss0 = 0.f, ss1 = 0.f;

    // prefetch W k-slice 0
    float4 w0a = *(const float4*)(wb0);
    float4 w0b = *(const float4*)(wb0 + 4);
    float4 w1a = *(const float4*)(wb1);
    float4 w1b = *(const float4*)(wb1 + 4);

    #pragma unroll
    for (int t = 0; t < NKT; ++t) {
        // A fragments for step t (L2-hot)
        bf16x8 af[4];
        #pragma unroll
        for (int i = 0; i < 4; i++)
            af[i] = *(const bf16x8*)(abase[i] + t * BK);
        // W prefetch for t+1 (cold stream; issued a full step before use)
        float4 n0a, n0b, n1a, n1b;
        if (t + 1 < NKT) {
            n0a = *(const float4*)(wb0 + (t + 1) * BK);
            n0b = *(const float4*)(wb0 + (t + 1) * BK + 4);
            n1a = *(const float4*)(wb1 + (t + 1) * BK);
            n1b = *(const float4*)(wb1 + (t + 1) * BK + 4);
        }
        // ||w||^2 partials (f32, full precision)
        ss0 += w0a.x*w0a.x + w0a.y*w0a.y + w0a.z*w0a.z + w0a.w*w0a.w
             + w0b.x*w0b.x + w0b.y*w0b.y + w0b.z*w0b.z + w0b.w*w0b.w;
        ss1 += w1a.x*w1a.x + w1a.y*w1a.y + w1a.z*w1a.z + w1a.w*w1a.w
             + w1b.x*w1b.x + w1b.y*w1b.y + w1b.z*w1b.z + w1b.w*w1b.w;
        // cvt to bf16 B-fragments
        union { unsigned int u[4]; bf16x8 v; } b0, b1;
        b0.u[0] = cvtpk(w0a.x, w0a.y); b0.u[1] = cvtpk(w0a.z, w0a.w);
        b0.u[2] = cvtpk(w0b.x, w0b.y); b0.u[3] = cvtpk(w0b.z, w0b.w);
        b1.u[0] = cvtpk(w1a.x, w1a.y); b1.u[1] = cvtpk(w1a.z, w1a.w);
        b1.u[2] = cvtpk(w1b.x, w1b.y); b1.u[3] = cvtpk(w1b.z, w1b.w);
        // MFMA
        #pragma unroll
        for (int i = 0; i < 4; i++) {
            acc[i][0] = __builtin_amdgcn_mfma_f32_16x16x32_bf16(af[i], b0.v, acc[i][0], 0, 0, 0);
            acc[i][1] = __builtin_amdgcn_mfma_f32_16x16x32_bf16(af[i], b1.v, acc[i][1], 0, 0, 0);
        }
        w0a = n0a; w0b = n0b; w1a = n1a; w1b = n1b;
    }

    // finish ||w||^2 across the 4 quads (lane bits 4,5); every lane then holds
    // winv for exactly the classes its C/D columns correspond to.
    ss0 += __shfl_xor(ss0, 16); ss0 += __shfl_xor(ss0, 32);
    ss1 += __shfl_xor(ss1, 16); ss1 += __shfl_xor(ss1, 32);
    float wv0 = SCALE / fmaxf(sqrtf(ss0), EPSN);
    float wv1 = SCALE / fmaxf(sqrtf(ss1), EPSN);

    // epilogue: partial softmax over this wave's 32 cols; transposed partials
    // ([tile2][row]) so a wave's 16 stores per i land contiguous (no write-amp).
    int tile2 = blockIdx.y * 2 + wc;
    #pragma unroll
    for (int i = 0; i < 4; i++) {
        #pragma unroll
        for (int r = 0; r < 4; r++) {
            int row_g = m0 + wr * 64 + i * 16 + quad * 4 + r;
            float v0 = valid0 ? acc[i][0][r] * wv0 : -1e30f;
            float v1 = valid1 ? acc[i][1][r] * wv1 : -1e30f;
            float m = fmaxf(v0, v1);
            #pragma unroll
            for (int msk = 1; msk < 16; msk <<= 1) m = fmaxf(m, __shfl_xor(m, msk));
            float s = expf(v0 - m) + expf(v1 - m);
            #pragma unroll
            for (int msk = 1; msk < 16; msk <<= 1) s += __shfl_xor(s, msk);
            if (lr == 0)
                partials[(size_t)tile2 * B_ROWS + row_g] = make_float2(m, s);
        }
    }
}

// ---------- merge partials -> LSE, fused label logit -> mean NLL ----------
__global__ void reduce_loss(const float2* __restrict__ partials,
                            const unsigned short* __restrict__ xnb,
                            const float* __restrict__ w,
                            const int* __restrict__ label,
                            float* __restrict__ out) {
    __shared__ float sm[256], ssum[256];
    __shared__ float tsh;
    int row = blockIdx.x, tid = threadIdx.x;

    // label logit (bf16-consistent with GEMM): 256 threads x 2 elements
    {
        int lab = label[row];
        const float* wr = w + (size_t)lab * D_DIM + tid * 2;
        const unsigned short* xr = xnb + (size_t)row * D_DIM + tid * 2;
        float w0 = wr[0], w1 = wr[1];
        float dot = bf2f(f2bf(w0)) * bf2f(xr[0]) + bf2f(f2bf(w1)) * bf2f(xr[1]);
        float ssl = w0 * w0 + w1 * w1;
        sm[tid] = dot; ssum[tid] = ssl;
        __syncthreads();
        for (int off = 128; off > 0; off >>= 1) {
            if (tid < off) { sm[tid] += sm[tid + off]; ssum[tid] += ssum[tid + off]; }
            __syncthreads();
        }
        if (tid == 0) tsh = sm[0] * SCALE / fmaxf(sqrtf(ssum[0]), EPSN);
        __syncthreads();
    }

    float m = -INFINITY, s = 0.f;
    for (int idx = tid; idx < NT2; idx += 256) {
        float2 p = partials[(size_t)idx * B_ROWS + row];
        if (p.x > m) { s = s * expf(m - p.x) + p.y; m = p.x; }
        else         { s += p.y * expf(p.x - m); }
    }
    sm[tid] = m; ssum[tid] = s;
    __syncthreads();
    for (int off = 128; off > 0; off >>= 1) {
        if (tid < off) {
            float m2 = sm[tid + off], s2 = ssum[tid + off];
            float mm = fmaxf(m, m2);
            s = s * expf(m - mm) + s2 * expf(m2 - mm);
            m = mm;
            sm[tid] = m; ssum[tid] = s;
        }
        __syncthreads();
    }
    if (tid == 0) {
        float lse = m + logf(s);
        atomicAdd(out, (lse - tsh) * (1.0f / (float)B_ROWS));
    }
}

extern "C" void kernel_launch(void* const* d_in, const int* in_sizes, int n_in,
                              void* d_out, int out_size, void* d_ws, size_t ws_size,
                              hipStream_t stream) {
    const float* x     = (const float*)d_in[0];
    const float* w     = (const float*)d_in[1];
    const int*   label = (const int*)d_in[2];
    float* out = (float*)d_out;

    char* ws = (char*)d_ws;
    unsigned short* xnb = (unsigned short*)ws;                 // 524288 B
    float2* partials    = (float2*)(ws + 524288);              // 3126*512*8 = 12804096 B

    hipMemsetAsync(d_out, 0, sizeof(float), stream);
    normalize_x<<<B_ROWS, 64, 0, stream>>>(x, xnb);
    gemm_fused<<<dim3(2, NTILE), 512, 0, stream>>>(xnb, w, partials);
    reduce_loss<<<B_ROWS, 256, 0, stream>>>(partials, xnb, w, label, out);
}

// Round 5
// 552.657 us; speedup vs baseline: 1.1220x; 1.1220x over previous
//
#include <hip/hip_runtime.h>
#include <math.h>

#define B_ROWS 512
#define D_DIM  512
#define C_CLS  100000
#define SCALE  64.0f
#define EPSN   1e-12f

#define NG  1563            // class groups of 64 (ceil(100000/64))
#define NT2 (NG * 2)        // 32-class partial groups per row

typedef __attribute__((ext_vector_type(8)))  short bf16x8;
typedef __attribute__((ext_vector_type(16))) float f32x16;

__device__ inline unsigned short f2bf(float f) {
    union { float f; unsigned int u; } v; v.f = f;
    unsigned int r = v.u + 0x7fffu + ((v.u >> 16) & 1u);
    return (unsigned short)(r >> 16);
}
__device__ inline float bf2f(unsigned short h) {
    union { unsigned int u; float f; } v; v.u = ((unsigned int)h) << 16;
    return v.f;
}

// ---------- normalize x rows, store bf16 row-major ----------
__global__ void normalize_x(const float* __restrict__ x, unsigned short* __restrict__ xnb) {
    int row  = blockIdx.x;
    int lane = threadIdx.x;  // 64
    const float4* xr = (const float4*)(x + (size_t)row * D_DIM);
    float4 a = xr[lane];
    float4 b = xr[lane + 64];
    float ss = a.x*a.x + a.y*a.y + a.z*a.z + a.w*a.w
             + b.x*b.x + b.y*b.y + b.z*b.z + b.w*b.w;
    #pragma unroll
    for (int m = 1; m < 64; m <<= 1) ss += __shfl_xor(ss, m);
    float inv = 1.0f / fmaxf(sqrtf(ss), EPSN);
    ushort4 o0, o1;
    o0.x = f2bf(a.x*inv); o0.y = f2bf(a.y*inv); o0.z = f2bf(a.z*inv); o0.w = f2bf(a.w*inv);
    o1.x = f2bf(b.x*inv); o1.y = f2bf(b.y*inv); o1.z = f2bf(b.z*inv); o1.w = f2bf(b.w*inv);
    ushort4* orow = (ushort4*)(xnb + (size_t)row * D_DIM);
    orow[lane]      = o0;
    orow[lane + 64] = o1;
}

// ---------- W -> fragment-major, norm-baked bf16 ----------
// Per 64-class group g: layout wnb[g][q][cc][e] (q = k>>3 in 0..63, cc = class&63,
// e = k&7), i.e. a wave's 32x32x16 B-fragment load is 2 contiguous 512B segments.
// Values are bf16(w * S/||w||) -- scaling baked, f32-norm precision.
// Invalid classes (group 1562 tail) are written as zeros.
__global__ __launch_bounds__(512, 4) void w_frag(const float* __restrict__ w,
                                                 unsigned short* __restrict__ wnb) {
    __shared__ unsigned short lds[64 * 512];   // 64 KB fragment-major tile
    int g   = blockIdx.x;
    int tid = threadIdx.x;
    int cc  = tid >> 3;          // class within group
    int h   = tid & 7;           // 8 threads per class
    int c   = g * 64 + cc;
    int vld = c < C_CLS;
    const float4* wr = (const float4*)(w + (size_t)(vld ? c : (C_CLS - 1)) * D_DIM) + h;
    float4 v[16];
    float ss = 0.f;
    #pragma unroll
    for (int jj = 0; jj < 16; ++jj) {
        float4 t = wr[jj * 8];               // k = h*4 + jj*32
        if (!vld) { t.x = 0.f; t.y = 0.f; t.z = 0.f; t.w = 0.f; }
        v[jj] = t;
        ss += t.x*t.x + t.y*t.y + t.z*t.z + t.w*t.w;
    }
    ss += __shfl_xor(ss, 1); ss += __shfl_xor(ss, 2); ss += __shfl_xor(ss, 4);
    float s = SCALE / fmaxf(sqrtf(ss), EPSN);
    #pragma unroll
    for (int jj = 0; jj < 16; ++jj) {
        int k = h * 4 + jj * 32;
        int q = k >> 3, e = k & 7;
        ushort4 o;
        o.x = f2bf(v[jj].x * s); o.y = f2bf(v[jj].y * s);
        o.z = f2bf(v[jj].z * s); o.w = f2bf(v[jj].w * s);
        *(ushort4*)(lds + (q * 64 + cc) * 8 + e) = o;
    }
    __syncthreads();
    // coalesced linear copy out (LDS already holds fragment-major order)
    uint4* dst = (uint4*)(wnb + (size_t)g * 32768);
    const uint4* src = (const uint4*)lds;
    #pragma unroll
    for (int i2 = 0; i2 < 8; ++i2)
        dst[i2 * 512 + tid] = src[i2 * 512 + tid];
}

// ---------- barrier-free register GEMM (32x32x16 MFMA) + partial softmax ----------
// Block: BM=256 rows x 64 classes; 512 threads = 8 waves (4M x 2N); wave tile 64x32.
// A: direct from xnb (L2-resident). B: fragment-major wnb (L3-resident, coalesced).
// Explicit depth-2 register prefetch; no LDS, no __syncthreads -> counted vmcnt only.
__global__ __launch_bounds__(512, 4) void gemm_nb(const unsigned short* __restrict__ xnb,
                                                  const unsigned short* __restrict__ wnb,
                                                  float2* __restrict__ partials) {
    int tid = threadIdx.x;
    int m0  = blockIdx.x * 256;
    int g   = blockIdx.y;
    int wid = tid >> 6, lane = tid & 63;
    int lo5 = lane & 31, hi = lane >> 5;
    int wr  = wid >> 1, wc = wid & 1;

    f32x16 acc[2];
    #pragma unroll
    for (int i = 0; i < 2; i++)
        #pragma unroll
        for (int r = 0; r < 16; r++) acc[i][r] = 0.f;

    // A: lane holds row (lo5), k = hi*8 + e ; i = which 32-row subtile
    const unsigned short* aptr[2];
    #pragma unroll
    for (int i = 0; i < 2; i++)
        aptr[i] = xnb + (size_t)(m0 + wr * 64 + i * 32 + lo5) * D_DIM + hi * 8;
    // B: lane holds col/class (wc*32+lo5), k-chunk q = t*4 + s*2 + hi
    const unsigned short* bptr = wnb + (size_t)g * 32768 + (hi * 64 + wc * 32 + lo5) * 8;

    bf16x8 ab[2][2][2];   // [buf][i][s]
    bf16x8 bb[2][2];      // [buf][s]
    #pragma unroll
    for (int p = 0; p < 2; p++) {
        #pragma unroll
        for (int i = 0; i < 2; i++)
            #pragma unroll
            for (int s2 = 0; s2 < 2; s2++)
                ab[p][i][s2] = *(const bf16x8*)(aptr[i] + p * 32 + s2 * 16);
        #pragma unroll
        for (int s2 = 0; s2 < 2; s2++)
            bb[p][s2] = *(const bf16x8*)(bptr + (p * 4 + s2 * 2) * 512);
    }

    #pragma unroll
    for (int t = 0; t < 16; ++t) {
        int cur = t & 1;
        bf16x8 na[2][2], nb[2];
        if (t + 2 < 16) {   // issue prefetch for t+2 before this step's MFMAs
            #pragma unroll
            for (int i = 0; i < 2; i++)
                #pragma unroll
                for (int s2 = 0; s2 < 2; s2++)
                    na[i][s2] = *(const bf16x8*)(aptr[i] + (t + 2) * 32 + s2 * 16);
            #pragma unroll
            for (int s2 = 0; s2 < 2; s2++)
                nb[s2] = *(const bf16x8*)(bptr + ((t + 2) * 4 + s2 * 2) * 512);
        }
        #pragma unroll
        for (int s2 = 0; s2 < 2; s2++)
            #pragma unroll
            for (int i = 0; i < 2; i++)
                acc[i] = __builtin_amdgcn_mfma_f32_32x32x16_bf16(ab[cur][i][s2], bb[cur][s2], acc[i], 0, 0, 0);
        if (t + 2 < 16) {
            #pragma unroll
            for (int i = 0; i < 2; i++)
                #pragma unroll
                for (int s2 = 0; s2 < 2; s2++)
                    ab[cur][i][s2] = na[i][s2];
            #pragma unroll
            for (int s2 = 0; s2 < 2; s2++)
                bb[cur][s2] = nb[s2];
        }
    }

    // epilogue: logits are final (scaling baked into wnb). Per-row partial softmax
    // over this wave's 32 classes: for fixed reg, the 32 lanes of a half-wave hold
    // one row's 32 cols -> 5-step shfl reduce. Transposed partials (no write-amp).
    int cj    = g * 64 + wc * 32 + lo5;
    int valid = cj < C_CLS;
    int tile2 = g * 2 + wc;
    #pragma unroll
    for (int i = 0; i < 2; i++) {
        #pragma unroll
        for (int r = 0; r < 16; r++) {
            int row_g = m0 + wr * 64 + i * 32 + (r & 3) + ((r >> 2) << 3) + (hi << 2);
            float v = valid ? acc[i][r] : -1e30f;
            float m = v;
            #pragma unroll
            for (int msk = 1; msk < 32; msk <<= 1) m = fmaxf(m, __shfl_xor(m, msk));
            float sum = expf(v - m);
            #pragma unroll
            for (int msk = 1; msk < 32; msk <<= 1) sum += __shfl_xor(sum, msk);
            if (lo5 == 0)
                partials[(size_t)tile2 * B_ROWS + row_g] = make_float2(m, sum);
        }
    }
}

// ---------- merge partials -> LSE, fused label logit -> mean NLL ----------
__global__ void reduce_loss(const float2* __restrict__ partials,
                            const unsigned short* __restrict__ xnb,
                            const unsigned short* __restrict__ wnb,
                            const int* __restrict__ label,
                            float* __restrict__ out) {
    __shared__ float sm[256], ssum[256];
    __shared__ float tsh;
    int row = blockIdx.x, tid = threadIdx.x;

    // label logit from the SAME baked wnb values the GEMM consumed
    {
        int lab = label[row];
        int g = lab >> 6, cc = lab & 63;
        int q = tid >> 2, e = (tid & 3) * 2;   // k = tid*2, tid*2+1
        const unsigned short* wp = wnb + (size_t)g * 32768 + (q * 64 + cc) * 8 + e;
        const unsigned short* xp = xnb + (size_t)row * D_DIM + tid * 2;
        float dot = bf2f(wp[0]) * bf2f(xp[0]) + bf2f(wp[1]) * bf2f(xp[1]);
        sm[tid] = dot;
        __syncthreads();
        for (int off = 128; off > 0; off >>= 1) {
            if (tid < off) sm[tid] += sm[tid + off];
            __syncthreads();
        }
        if (tid == 0) tsh = sm[0];
        __syncthreads();
    }

    float m = -INFINITY, s = 0.f;
    for (int idx = tid; idx < NT2; idx += 256) {
        float2 p = partials[(size_t)idx * B_ROWS + row];
        if (p.x > m) { s = s * expf(m - p.x) + p.y; m = p.x; }
        else         { s += p.y * expf(p.x - m); }
    }
    sm[tid] = m; ssum[tid] = s;
    __syncthreads();
    for (int off = 128; off > 0; off >>= 1) {
        if (tid < off) {
            float m2 = sm[tid + off], s2 = ssum[tid + off];
            float mm = fmaxf(m, m2);
            s = s * expf(m - mm) + s2 * expf(m2 - mm);
            m = mm;
            sm[tid] = m; ssum[tid] = s;
        }
        __syncthreads();
    }
    if (tid == 0) {
        float lse = m + logf(s);
        atomicAdd(out, (lse - tsh) * (1.0f / (float)B_ROWS));
    }
}

extern "C" void kernel_launch(void* const* d_in, const int* in_sizes, int n_in,
                              void* d_out, int out_size, void* d_ws, size_t ws_size,
                              hipStream_t stream) {
    const float* x     = (const float*)d_in[0];
    const float* w     = (const float*)d_in[1];
    const int*   label = (const int*)d_in[2];
    float* out = (float*)d_out;

    char* ws = (char*)d_ws;
    unsigned short* xnb = (unsigned short*)ws;                 // 524288 B
    float2* partials    = (float2*)(ws + 524288);              // 3126*512*8 = 12804096 B -> ends 13328384
    unsigned short* wnb = (unsigned short*)(ws + 13328384);    // 1563*32768*2 = 102432768 B -> ends 115761152

    hipMemsetAsync(d_out, 0, sizeof(float), stream);
    normalize_x<<<B_ROWS, 64, 0, stream>>>(x, xnb);
    w_frag<<<NG, 512, 0, stream>>>(w, wnb);
    gemm_nb<<<dim3(2, NG), 512, 0, stream>>>(xnb, wnb, partials);
    reduce_loss<<<B_ROWS, 256, 0, stream>>>(partials, xnb, wnb, label, out);
}

// Round 6
// 492.011 us; speedup vs baseline: 1.2603x; 1.1233x over previous
//
#include <hip/hip_runtime.h>
#include <math.h>

#define B_ROWS 512
#define D_DIM  512
#define C_CLS  100000
#define SCALE  64.0f
#define EPSN   1e-12f

#define NG    1563          // class groups of 64
#define NPAIR 782           // ceil(NG/2)
#define NBY   64            // y-grid

typedef __attribute__((ext_vector_type(8)))  short bf16x8;
typedef __attribute__((ext_vector_type(16))) float f32x16;

__device__ inline unsigned short f2bf(float f) {
    union { float f; unsigned int u; } v; v.f = f;
    unsigned int r = v.u + 0x7fffu + ((v.u >> 16) & 1u);
    return (unsigned short)(r >> 16);
}
__device__ inline float bf2f(unsigned short h) {
    union { unsigned int u; float f; } v; v.u = ((unsigned int)h) << 16;
    return v.f;
}

// ---------- normalize x rows -> FRAGMENT-MAJOR bf16 ----------
// Layout: xnb[mblk][q][rr][e], mblk = row>>7, q = k>>3 (64), rr = row&127, e = k&7.
// A wave's 32x32x16 A-fragment read (and the GEMM's LDS staging) is then linear.
__global__ void normalize_x(const float* __restrict__ x, unsigned short* __restrict__ xnb) {
    int row  = blockIdx.x;
    int lane = threadIdx.x;  // 64; lane == q
    const float4* xr = (const float4*)(x + (size_t)row * D_DIM);
    float4 a = xr[2 * lane];
    float4 b = xr[2 * lane + 1];
    float ss = a.x*a.x + a.y*a.y + a.z*a.z + a.w*a.w
             + b.x*b.x + b.y*b.y + b.z*b.z + b.w*b.w;
    #pragma unroll
    for (int m = 1; m < 64; m <<= 1) ss += __shfl_xor(ss, m);
    float inv = 1.0f / fmaxf(sqrtf(ss), EPSN);
    unsigned int u0 = f2bf(a.x*inv) | ((unsigned int)f2bf(a.y*inv) << 16);
    unsigned int u1 = f2bf(a.z*inv) | ((unsigned int)f2bf(a.w*inv) << 16);
    unsigned int u2 = f2bf(b.x*inv) | ((unsigned int)f2bf(b.y*inv) << 16);
    unsigned int u3 = f2bf(b.z*inv) | ((unsigned int)f2bf(b.w*inv) << 16);
    uint4 u = make_uint4(u0, u1, u2, u3);
    int mblk = row >> 7, rr = row & 127;
    *(uint4*)(xnb + (size_t)mblk * 65536 + ((size_t)lane * 128 + rr) * 8) = u;
}

// ---------- W -> fragment-major, norm-baked bf16 (verified round 5) ----------
// wnb[g][q][cc][e]: q = k>>3 (64), cc = class&63, e = k&7. Values bf16(w * S/||w||),
// invalid tail classes zeroed.
__global__ __launch_bounds__(512, 4) void w_frag(const float* __restrict__ w,
                                                 unsigned short* __restrict__ wnb) {
    __shared__ unsigned short lds[64 * 512];   // 64 KB
    int g   = blockIdx.x;
    int tid = threadIdx.x;
    int cc  = tid >> 3;
    int h   = tid & 7;
    int c   = g * 64 + cc;
    int vld = c < C_CLS;
    const float4* wr = (const float4*)(w + (size_t)(vld ? c : (C_CLS - 1)) * D_DIM) + h;
    float4 v[16];
    float ss = 0.f;
    #pragma unroll
    for (int jj = 0; jj < 16; ++jj) {
        float4 t = wr[jj * 8];               // k = h*4 + jj*32
        if (!vld) { t.x = 0.f; t.y = 0.f; t.z = 0.f; t.w = 0.f; }
        v[jj] = t;
        ss += t.x*t.x + t.y*t.y + t.z*t.z + t.w*t.w;
    }
    ss += __shfl_xor(ss, 1); ss += __shfl_xor(ss, 2); ss += __shfl_xor(ss, 4);
    float s = SCALE / fmaxf(sqrtf(ss), EPSN);
    #pragma unroll
    for (int jj = 0; jj < 16; ++jj) {
        int k = h * 4 + jj * 32;
        int q = k >> 3, e = k & 7;
        ushort4 o;
        o.x = f2bf(v[jj].x * s); o.y = f2bf(v[jj].y * s);
        o.z = f2bf(v[jj].z * s); o.w = f2bf(v[jj].w * s);
        *(ushort4*)(lds + (q * 64 + cc) * 8 + e) = o;
    }
    __syncthreads();
    uint4* dst = (uint4*)(wnb + (size_t)g * 32768);
    const uint4* src = (const uint4*)lds;
    #pragma unroll
    for (int i2 = 0; i2 < 8; ++i2)
        dst[i2 * 512 + tid] = src[i2 * 512 + tid];
}

// ---------- persistent-A GEMM: barrier-free K-loop, deep rotating B prefetch ----------
// Block = 128-row m-slice (LDS 128KB, staged once) x stream of 64-class groups.
// 8 waves = 4 m-subtiles x 2 group-slots. Per wave per group: 32 k16-steps of
// {1 ds_read_b128 (A), 2 global b128 (B, depth-7 rotation), 2 mfma_32x32x16}.
// Only ONE __syncthreads in the whole kernel (after A staging).
__global__ __launch_bounds__(512, 2) void gemm_pa(const unsigned short* __restrict__ xnb,
                                                  const unsigned short* __restrict__ wnb,
                                                  float2* __restrict__ partials) {
    __shared__ unsigned short As[64 * 128 * 8];   // 128 KB fragment-major [q][row][e]

    int tid  = threadIdx.x;
    int mblk = blockIdx.x;            // 0..3
    int y    = blockIdx.y;            // 0..NBY-1
    int wid  = tid >> 6, lane = tid & 63;
    int lo5  = lane & 31, hi = lane >> 5;
    int wr   = wid >> 1;              // m-subtile (32 rows)
    int ws   = wid & 1;               // group slot

    // ---- one-time A staging: linear copy (both sides fragment-major) ----
    {
        const unsigned short* src = xnb + (size_t)mblk * 65536;
        #pragma unroll
        for (int it = 0; it < 16; ++it) {
            int c = it * 512 + tid;
            __builtin_amdgcn_global_load_lds(
                (const __attribute__((address_space(1))) void*)(src + (size_t)c * 8),
                (__attribute__((address_space(3))) void*)(As + (it * 512 + wid * 64) * 8),
                16, 0, 0);
        }
    }
    __syncthreads();

    // per-lane fragment bases (ushort offsets)
    const unsigned short* ALds = As + hi * 1024 + wr * 256 + lo5 * 8;   // + s*2048

    f32x16 acc0, acc1;
    #pragma unroll
    for (int r = 0; r < 16; r++) { acc0[r] = 0.f; acc1[r] = 0.f; }

    bf16x8 bb[8][2];
    bf16x8 ab[4];

    int p = y;
    int g = 2 * p + ws;
    const unsigned short* bp = wnb + (size_t)((g < NG) ? g : 0) * 32768 + hi * 512 + lo5 * 8;

    // prologue: B steps 0..6 of first group, A steps 0..2
    #pragma unroll
    for (int s = 0; s < 7; ++s) {
        bb[s][0] = *(const bf16x8*)(bp + s * 1024);
        bb[s][1] = *(const bf16x8*)(bp + s * 1024 + 256);
    }
    #pragma unroll
    for (int s = 0; s < 3; ++s) ab[s] = *(const bf16x8*)(ALds + s * 2048);

    for (; p < NPAIR; p += NBY) {
        int pn = p + NBY;
        int gn = 2 * pn + ws;
        const unsigned short* bpn =
            wnb + (size_t)((pn < NPAIR && gn < NG) ? gn : 0) * 32768 + hi * 512 + lo5 * 8;

        #pragma unroll
        for (int t = 0; t < 32; ++t) {
            // B prefetch for step t+7 (seamlessly crosses into next group)
            if (t + 7 < 32) {
                bb[(t + 7) & 7][0] = *(const bf16x8*)(bp + (t + 7) * 1024);
                bb[(t + 7) & 7][1] = *(const bf16x8*)(bp + (t + 7) * 1024 + 256);
            } else {
                bb[(t + 7) & 7][0] = *(const bf16x8*)(bpn + (t - 25) * 1024);
                bb[(t + 7) & 7][1] = *(const bf16x8*)(bpn + (t - 25) * 1024 + 256);
            }
            // A prefetch for step t+3 (A identical across groups -> wraps mod 32)
            ab[(t + 3) & 3] = *(const bf16x8*)(ALds + ((t + 3) & 31) * 2048);
            acc0 = __builtin_amdgcn_mfma_f32_32x32x16_bf16(ab[t & 3], bb[t & 7][0], acc0, 0, 0, 0);
            acc1 = __builtin_amdgcn_mfma_f32_32x32x16_bf16(ab[t & 3], bb[t & 7][1], acc1, 0, 0, 0);
        }

        // epilogue: partial softmax over this wave's 64 classes of group g
        if (g < NG) {
            int v0ok = (g * 64 + lo5)      < C_CLS;
            int v1ok = (g * 64 + 32 + lo5) < C_CLS;
            #pragma unroll
            for (int r = 0; r < 16; ++r) {
                float v0 = v0ok ? acc0[r] : -1e30f;
                float v1 = v1ok ? acc1[r] : -1e30f;
                float m = fmaxf(v0, v1);
                #pragma unroll
                for (int msk = 1; msk < 32; msk <<= 1) m = fmaxf(m, __shfl_xor(m, msk));
                float s = expf(v0 - m) + expf(v1 - m);
                #pragma unroll
                for (int msk = 1; msk < 32; msk <<= 1) s += __shfl_xor(s, msk);
                if (lo5 == 0) {
                    int row_g = mblk * 128 + wr * 32 + (r & 3) + ((r >> 2) << 3) + (hi << 2);
                    partials[(size_t)g * B_ROWS + row_g] = make_float2(m, s);
                }
            }
        }
        #pragma unroll
        for (int r = 0; r < 16; r++) { acc0[r] = 0.f; acc1[r] = 0.f; }
        g = gn; bp = bpn;
    }
}

// ---------- merge partials -> LSE, fused label logit -> mean NLL ----------
__global__ void reduce_loss(const float2* __restrict__ partials,
                            const unsigned short* __restrict__ xnb,
                            const unsigned short* __restrict__ wnb,
                            const int* __restrict__ label,
                            float* __restrict__ out) {
    __shared__ float sm[256], ssum[256];
    __shared__ float tsh;
    int row = blockIdx.x, tid = threadIdx.x;

    // label logit from the SAME baked wnb / fragment-major xnb values
    {
        int lab = label[row];
        int gg = lab >> 6, cc = lab & 63;
        int q = tid >> 2, e = (tid & 3) * 2;   // k = tid*2, tid*2+1
        const unsigned short* wp = wnb + (size_t)gg * 32768 + (q * 64 + cc) * 8 + e;
        const unsigned short* xp = xnb + (size_t)(row >> 7) * 65536 + ((size_t)q * 128 + (row & 127)) * 8 + e;
        float dot = bf2f(wp[0]) * bf2f(xp[0]) + bf2f(wp[1]) * bf2f(xp[1]);
        sm[tid] = dot;
        __syncthreads();
        for (int off = 128; off > 0; off >>= 1) {
            if (tid < off) sm[tid] += sm[tid + off];
            __syncthreads();
        }
        if (tid == 0) tsh = sm[0];
        __syncthreads();
    }

    float m = -INFINITY, s = 0.f;
    for (int idx = tid; idx < NG; idx += 256) {
        float2 p = partials[(size_t)idx * B_ROWS + row];
        if (p.x > m) { s = s * expf(m - p.x) + p.y; m = p.x; }
        else         { s += p.y * expf(p.x - m); }
    }
    sm[tid] = m; ssum[tid] = s;
    __syncthreads();
    for (int off = 128; off > 0; off >>= 1) {
        if (tid < off) {
            float m2 = sm[tid + off], s2 = ssum[tid + off];
            float mm = fmaxf(m, m2);
            s = s * expf(m - mm) + s2 * expf(m2 - mm);
            m = mm;
            sm[tid] = m; ssum[tid] = s;
        }
        __syncthreads();
    }
    if (tid == 0) {
        float lse = m + logf(s);
        atomicAdd(out, (lse - tsh) * (1.0f / (float)B_ROWS));
    }
}

extern "C" void kernel_launch(void* const* d_in, const int* in_sizes, int n_in,
                              void* d_out, int out_size, void* d_ws, size_t ws_size,
                              hipStream_t stream) {
    const float* x     = (const float*)d_in[0];
    const float* w     = (const float*)d_in[1];
    const int*   label = (const int*)d_in[2];
    float* out = (float*)d_out;

    char* ws = (char*)d_ws;
    unsigned short* xnb = (unsigned short*)ws;                 // 524288 B
    float2* partials    = (float2*)(ws + 524288);              // 1563*512*8 = 6402048 B -> ends 6926336
    unsigned short* wnb = (unsigned short*)(ws + 6926336);     // 102432768 B -> ends 109359104

    hipMemsetAsync(d_out, 0, sizeof(float), stream);
    normalize_x<<<B_ROWS, 64, 0, stream>>>(x, xnb);
    w_frag<<<NG, 512, 0, stream>>>(w, wnb);
    gemm_pa<<<dim3(4, NBY), 512, 0, stream>>>(xnb, wnb, partials);
    reduce_loss<<<B_ROWS, 256, 0, stream>>>(partials, xnb, wnb, label, out);
}

// Round 7
// 431.790 us; speedup vs baseline: 1.4360x; 1.1395x over previous
//
#include <hip/hip_runtime.h>
#include <math.h>

#define B_ROWS 512
#define D_DIM  512
#define C_CLS  100000
#define SCALE  64.0f
#define EPSN   1e-12f

#define NG 1563             // class groups of 64

typedef __attribute__((ext_vector_type(8)))  short bf16x8;
typedef __attribute__((ext_vector_type(16))) float f32x16;

__device__ inline unsigned short f2bf(float f) {
    union { float f; unsigned int u; } v; v.f = f;
    unsigned int r = v.u + 0x7fffu + ((v.u >> 16) & 1u);
    return (unsigned short)(r >> 16);
}
__device__ inline float bf2f(unsigned short h) {
    union { unsigned int u; float f; } v; v.u = ((unsigned int)h) << 16;
    return v.f;
}

// ---------- normalize x rows -> FRAGMENT-MAJOR bf16 ----------
// Layout: xnb[mblk][q][rr][e], mblk = row>>7, q = k>>3 (64), rr = row&127, e = k&7.
__global__ void normalize_x(const float* __restrict__ x, unsigned short* __restrict__ xnb) {
    int row  = blockIdx.x;
    int lane = threadIdx.x;  // 64; lane == q
    const float4* xr = (const float4*)(x + (size_t)row * D_DIM);
    float4 a = xr[2 * lane];
    float4 b = xr[2 * lane + 1];
    float ss = a.x*a.x + a.y*a.y + a.z*a.z + a.w*a.w
             + b.x*b.x + b.y*b.y + b.z*b.z + b.w*b.w;
    #pragma unroll
    for (int m = 1; m < 64; m <<= 1) ss += __shfl_xor(ss, m);
    float inv = 1.0f / fmaxf(sqrtf(ss), EPSN);
    unsigned int u0 = f2bf(a.x*inv) | ((unsigned int)f2bf(a.y*inv) << 16);
    unsigned int u1 = f2bf(a.z*inv) | ((unsigned int)f2bf(a.w*inv) << 16);
    unsigned int u2 = f2bf(b.x*inv) | ((unsigned int)f2bf(b.y*inv) << 16);
    unsigned int u3 = f2bf(b.z*inv) | ((unsigned int)f2bf(b.w*inv) << 16);
    uint4 u = make_uint4(u0, u1, u2, u3);
    int mblk = row >> 7, rr = row & 127;
    *(uint4*)(xnb + (size_t)mblk * 65536 + ((size_t)lane * 128 + rr) * 8) = u;
}

// ---------- W -> fragment-major, norm-baked bf16 (verified) ----------
// wnb[g][q][cc][e]: q = k>>3 (64), cc = class&63, e = k&7. Values bf16(w * S/||w||),
// invalid tail classes zeroed.
__global__ __launch_bounds__(512, 4) void w_frag(const float* __restrict__ w,
                                                 unsigned short* __restrict__ wnb) {
    __shared__ unsigned short lds[64 * 512];   // 64 KB
    int g   = blockIdx.x;
    int tid = threadIdx.x;
    int cc  = tid >> 3;
    int h   = tid & 7;
    int c   = g * 64 + cc;
    int vld = c < C_CLS;
    const float4* wr = (const float4*)(w + (size_t)(vld ? c : (C_CLS - 1)) * D_DIM) + h;
    float4 v[16];
    float ss = 0.f;
    #pragma unroll
    for (int jj = 0; jj < 16; ++jj) {
        float4 t = wr[jj * 8];               // k = h*4 + jj*32
        if (!vld) { t.x = 0.f; t.y = 0.f; t.z = 0.f; t.w = 0.f; }
        v[jj] = t;
        ss += t.x*t.x + t.y*t.y + t.z*t.z + t.w*t.w;
    }
    ss += __shfl_xor(ss, 1); ss += __shfl_xor(ss, 2); ss += __shfl_xor(ss, 4);
    float s = SCALE / fmaxf(sqrtf(ss), EPSN);
    #pragma unroll
    for (int jj = 0; jj < 16; ++jj) {
        int k = h * 4 + jj * 32;
        int q = k >> 3, e = k & 7;
        ushort4 o;
        o.x = f2bf(v[jj].x * s); o.y = f2bf(v[jj].y * s);
        o.z = f2bf(v[jj].z * s); o.w = f2bf(v[jj].w * s);
        *(ushort4*)(lds + (q * 64 + cc) * 8 + e) = o;
    }
    __syncthreads();
    uint4* dst = (uint4*)(wnb + (size_t)g * 32768);
    const uint4* src = (const uint4*)lds;
    #pragma unroll
    for (int i2 = 0; i2 < 8; ++i2)
        dst[i2 * 512 + tid] = src[i2 * 512 + tid];
}

// ---------- reg-direct GEMM: no LDS, no barriers, TLP-first ----------
// Block = 512 threads = 8 waves; wave w owns rows bx*256 + w*32 .. +32, all 64
// classes of group g. Per k16-step: {1 A b128 (L2-hot xnb), 2 B b128 (L3-hot wnb),
// 2 mfma_32x32x16}. B register rotation depth 6, A depth 2 -> ~115 VGPR, 4 waves/SIMD
// (2 blocks/CU): latency covered by TLP x moderate ILP, no vmcnt(0) drains anywhere.
__global__ __launch_bounds__(512, 4) void gemm_rd(const unsigned short* __restrict__ xnb,
                                                  const unsigned short* __restrict__ wnb,
                                                  float2* __restrict__ partials) {
    int tid = threadIdx.x;
    int bx  = blockIdx.x;          // 0..1 : 256-row m-slice
    int g   = blockIdx.y;          // class group
    int wid = tid >> 6, lane = tid & 63;
    int lo5 = lane & 31, hi = lane >> 5;

    // A: fragment-major xnb [mblk][q][rr][e]; this wave's rows = bx*256 + wid*32 + lo5
    int mblk = bx * 2 + (wid >> 2);
    int rr   = (wid & 3) * 32 + lo5;
    const unsigned short* ap = xnb + (size_t)mblk * 65536 + hi * 1024 + (size_t)rr * 8;
    // B: fragment-major wnb [g][q][cc][e]; classes g*64 + lo5 (+32)
    const unsigned short* bp = wnb + (size_t)g * 32768 + hi * 512 + lo5 * 8;

    f32x16 acc0, acc1;
    #pragma unroll
    for (int r = 0; r < 16; r++) { acc0[r] = 0.f; acc1[r] = 0.f; }

    bf16x8 bb[6][2], ab[2];
    #pragma unroll
    for (int s = 0; s < 6; ++s) {
        bb[s][0] = *(const bf16x8*)(bp + s * 1024);
        bb[s][1] = *(const bf16x8*)(bp + s * 1024 + 256);
    }
    ab[0] = *(const bf16x8*)(ap);
    ab[1] = *(const bf16x8*)(ap + 2048);

    #pragma unroll
    for (int t = 0; t < 32; ++t) {
        acc0 = __builtin_amdgcn_mfma_f32_32x32x16_bf16(ab[t & 1], bb[t % 6][0], acc0, 0, 0, 0);
        acc1 = __builtin_amdgcn_mfma_f32_32x32x16_bf16(ab[t & 1], bb[t % 6][1], acc1, 0, 0, 0);
        if (t + 6 < 32) {
            bb[t % 6][0] = *(const bf16x8*)(bp + (t + 6) * 1024);
            bb[t % 6][1] = *(const bf16x8*)(bp + (t + 6) * 1024 + 256);
        }
        if (t + 2 < 32) ab[t & 1] = *(const bf16x8*)(ap + (t + 2) * 2048);
    }

    // epilogue: partial softmax over this wave's 64 classes (scaling baked in wnb).
    // Classes live on lanes' lo5 within each 32-lane half; reduce with masks 1..16.
    int v0ok = (g * 64 + lo5)      < C_CLS;
    int v1ok = (g * 64 + 32 + lo5) < C_CLS;
    #pragma unroll
    for (int r = 0; r < 16; ++r) {
        float v0 = v0ok ? acc0[r] : -1e30f;
        float v1 = v1ok ? acc1[r] : -1e30f;
        float m = fmaxf(v0, v1);
        #pragma unroll
        for (int msk = 1; msk < 32; msk <<= 1) m = fmaxf(m, __shfl_xor(m, msk));
        float s = expf(v0 - m) + expf(v1 - m);
        #pragma unroll
        for (int msk = 1; msk < 32; msk <<= 1) s += __shfl_xor(s, msk);
        if (lo5 == 0) {
            int row_g = bx * 256 + wid * 32 + (r & 3) + ((r >> 2) << 3) + (hi << 2);
            partials[(size_t)g * B_ROWS + row_g] = make_float2(m, s);
        }
    }
}

// ---------- merge partials -> LSE, fused label logit -> mean NLL ----------
__global__ void reduce_loss(const float2* __restrict__ partials,
                            const unsigned short* __restrict__ xnb,
                            const unsigned short* __restrict__ wnb,
                            const int* __restrict__ label,
                            float* __restrict__ out) {
    __shared__ float sm[256], ssum[256];
    __shared__ float tsh;
    int row = blockIdx.x, tid = threadIdx.x;

    // label logit from the SAME baked wnb / fragment-major xnb values
    {
        int lab = label[row];
        int gg = lab >> 6, cc = lab & 63;
        int q = tid >> 2, e = (tid & 3) * 2;   // k = tid*2, tid*2+1
        const unsigned short* wp = wnb + (size_t)gg * 32768 + (q * 64 + cc) * 8 + e;
        const unsigned short* xp = xnb + (size_t)(row >> 7) * 65536 + ((size_t)q * 128 + (row & 127)) * 8 + e;
        float dot = bf2f(wp[0]) * bf2f(xp[0]) + bf2f(wp[1]) * bf2f(xp[1]);
        sm[tid] = dot;
        __syncthreads();
        for (int off = 128; off > 0; off >>= 1) {
            if (tid < off) sm[tid] += sm[tid + off];
            __syncthreads();
        }
        if (tid == 0) tsh = sm[0];
        __syncthreads();
    }

    float m = -INFINITY, s = 0.f;
    for (int idx = tid; idx < NG; idx += 256) {
        float2 p = partials[(size_t)idx * B_ROWS + row];
        if (p.x > m) { s = s * expf(m - p.x) + p.y; m = p.x; }
        else         { s += p.y * expf(p.x - m); }
    }
    sm[tid] = m; ssum[tid] = s;
    __syncthreads();
    for (int off = 128; off > 0; off >>= 1) {
        if (tid < off) {
            float m2 = sm[tid + off], s2 = ssum[tid + off];
            float mm = fmaxf(m, m2);
            s = s * expf(m - mm) + s2 * expf(m2 - mm);
            m = mm;
            sm[tid] = m; ssum[tid] = s;
        }
        __syncthreads();
    }
    if (tid == 0) {
        float lse = m + logf(s);
        atomicAdd(out, (lse - tsh) * (1.0f / (float)B_ROWS));
    }
}

extern "C" void kernel_launch(void* const* d_in, const int* in_sizes, int n_in,
                              void* d_out, int out_size, void* d_ws, size_t ws_size,
                              hipStream_t stream) {
    const float* x     = (const float*)d_in[0];
    const float* w     = (const float*)d_in[1];
    const int*   label = (const int*)d_in[2];
    float* out = (float*)d_out;

    char* ws = (char*)d_ws;
    unsigned short* xnb = (unsigned short*)ws;                 // 524288 B
    float2* partials    = (float2*)(ws + 524288);              // 1563*512*8 = 6402048 B -> ends 6926336
    unsigned short* wnb = (unsigned short*)(ws + 6926336);     // 102432768 B -> ends 109359104

    hipMemsetAsync(d_out, 0, sizeof(float), stream);
    normalize_x<<<B_ROWS, 64, 0, stream>>>(x, xnb);
    w_frag<<<NG, 512, 0, stream>>>(w, wnb);
    gemm_rd<<<dim3(2, NG), 512, 0, stream>>>(xnb, wnb, partials);
    reduce_loss<<<B_ROWS, 256, 0, stream>>>(partials, xnb, wnb, label, out);
}